// Round 1
// baseline (60.961 us; speedup 1.0000x reference)
//
#include <hip/hip_runtime.h>

constexpr int N = 512;
constexpr int D = 128;
constexpr float MARGIN = 1.0f;

// One block per anchor i:
//   1) stage anchor embedding e[i] (128 f32) and labels (512 i32) in LDS
//   2) compute distance row d[i][k] for all k into LDS (float4 loads; emb is
//      256 KB total -> L2-resident after first touch)
//   3) loop positives j (labels[j]==labels[i], j!=i); threads parallelize k;
//      accumulate hinge sum (f64), n_positive, n_triplets
//   4) deterministic LDS tree reduction -> per-block partials in d_ws
__global__ __launch_bounds__(256) void triplet_main_k(
    const float* __restrict__ emb, const int* __restrict__ labels,
    double* __restrict__ partial)
{
    __shared__ float  ei[D];
    __shared__ float  drow[N];
    __shared__ int    lab[N];
    __shared__ double rs[256], rp[256], rt[256];

    const int i   = blockIdx.x;
    const int tid = threadIdx.x;

    if (tid < D) ei[tid] = emb[i * D + tid];
    for (int k = tid; k < N; k += 256) lab[k] = labels[k];
    __syncthreads();

    // distance row: each thread handles 2 columns
    for (int k = tid; k < N; k += 256) {
        const float4* ek = reinterpret_cast<const float4*>(emb + k * D);
        const float4* ea = reinterpret_cast<const float4*>(ei);
        float sq = 0.f;
        #pragma unroll
        for (int t = 0; t < D / 4; ++t) {
            float4 v = ek[t];
            float4 a = ea[t];
            float d0 = a.x - v.x, d1 = a.y - v.y;
            float d2 = a.z - v.z, d3 = a.w - v.w;
            sq += d0 * d0 + d1 * d1 + d2 * d2 + d3 * d3;
        }
        // safe sqrt per reference: 0 when sq==0
        drow[k] = (sq > 0.f) ? sqrtf(sq) : 0.f;
    }
    __syncthreads();

    const int li = lab[i];
    double sum = 0.0, np = 0.0, nt = 0.0;

    for (int j = 0; j < N; ++j) {
        if (j == i || lab[j] != li) continue;      // j must be a distinct positive
        const float dij = drow[j];
        for (int k = tid; k < N; k += 256) {
            if (lab[k] != li) {                    // k must be a negative
                float t = dij - drow[k] + MARGIN;  // f32, matches reference math
                nt += 1.0;
                if (t > 1e-16f) {                  // EPS count; terms <=1e-16 are negligible in sum
                    sum += (double)t;
                    np  += 1.0;
                }
            }
        }
    }

    rs[tid] = sum; rp[tid] = np; rt[tid] = nt;
    __syncthreads();
    for (int off = 128; off > 0; off >>= 1) {
        if (tid < off) {
            rs[tid] += rs[tid + off];
            rp[tid] += rp[tid + off];
            rt[tid] += rt[tid + off];
        }
        __syncthreads();
    }
    if (tid == 0) {
        partial[i]         = rs[0];
        partial[N + i]     = rp[0];
        partial[2 * N + i] = rt[0];
    }
}

// Single-block deterministic final reduction + scalar outputs.
__global__ __launch_bounds__(256) void triplet_final_k(
    const double* __restrict__ partial, float* __restrict__ out)
{
    __shared__ double rs[256], rp[256], rt[256];
    const int tid = threadIdx.x;
    double a = 0.0, b = 0.0, c = 0.0;
    for (int k = tid; k < N; k += 256) {
        a += partial[k];
        b += partial[N + k];
        c += partial[2 * N + k];
    }
    rs[tid] = a; rp[tid] = b; rt[tid] = c;
    __syncthreads();
    for (int off = 128; off > 0; off >>= 1) {
        if (tid < off) {
            rs[tid] += rs[tid + off];
            rp[tid] += rp[tid + off];
            rt[tid] += rt[tid + off];
        }
        __syncthreads();
    }
    if (tid == 0) {
        const double sum   = rs[0];
        const double npos  = rp[0];
        const double ntrip = rt[0];
        out[0] = (float)(sum  / (npos  + 1e-16));  // loss
        out[1] = (float)(npos / (ntrip + 1e-16));  // fraction_positive
    }
}

extern "C" void kernel_launch(void* const* d_in, const int* in_sizes, int n_in,
                              void* d_out, int out_size, void* d_ws, size_t ws_size,
                              hipStream_t stream) {
    const float* emb   = (const float*)d_in[0];   // [512,128] f32
    const int*   lab   = (const int*)d_in[1];     // [512] i32
    float*       out   = (float*)d_out;           // [2] f32: loss, fraction_positive
    double*      parts = (double*)d_ws;           // 3*N doubles = 12 KB

    triplet_main_k<<<N, 256, 0, stream>>>(emb, lab, parts);
    triplet_final_k<<<1, 256, 0, stream>>>(parts, out);
}

// Round 2
// 25.854 us; speedup vs baseline: 2.3579x; 2.3579x over previous
//
#include <hip/hip_runtime.h>

constexpr int N = 512;
constexpr int D = 128;
constexpr float MARGIN = 1.0f;

// One block per anchor i.
// Phase 1: stage e[i] + labels; compute distance row d[i][*] into LDS.
// Phase 2: wave 0 compacts the positive index list via ballot (deterministic).
// Phase 3: stage positive distances; each thread covers 2 negatives k,
//          looping over ~16 positives -> ~32 hinge evals/thread.
// Phase 4: wave shuffle reduce (f64) + cross-wave merge -> per-block partials.
__global__ __launch_bounds__(256) void triplet_main_k(
    const float* __restrict__ emb, const int* __restrict__ labels,
    double* __restrict__ partial)
{
    __shared__ float  ei[D];
    __shared__ float  drow[N];
    __shared__ int    lab[N];
    __shared__ int    poslist[N];
    __shared__ float  posd[N];
    __shared__ int    npos_s;
    __shared__ double red[12];   // [0..3]=sum, [4..7]=npos, [8..11]=ntrip per wave

    const int i    = blockIdx.x;
    const int tid  = threadIdx.x;
    const int lane = tid & 63;
    const int wid  = tid >> 6;

    if (tid < D) ei[tid] = emb[(size_t)i * D + tid];
    const int l0 = labels[tid];        // label of k = tid
    const int l1 = labels[tid + 256];  // label of k = tid + 256
    lab[tid]       = l0;
    lab[tid + 256] = l1;
    __syncthreads();

    const int li = lab[i];

    // ---- Phase 1: distance row (2 rows per thread) ----
    const float4* ea = reinterpret_cast<const float4*>(ei);
    #pragma unroll
    for (int kk = 0; kk < 2; ++kk) {
        const int k = tid + kk * 256;
        const float4* ek = reinterpret_cast<const float4*>(emb + (size_t)k * D);
        float sq = 0.f;
        #pragma unroll
        for (int t = 0; t < D / 4; ++t) {
            float4 v = ek[t];
            float4 a = ea[t];
            float d0 = a.x - v.x, d1 = a.y - v.y;
            float d2 = a.z - v.z, d3 = a.w - v.w;
            sq += d0 * d0 + d1 * d1 + d2 * d2 + d3 * d3;
        }
        drow[k] = (sq > 0.f) ? sqrtf(sq) : 0.f;   // safe sqrt per reference
    }

    // ---- Phase 2: deterministic positive-list compaction (wave 0 only) ----
    if (wid == 0) {
        int base = 0;
        #pragma unroll
        for (int r = 0; r < 8; ++r) {
            const int j = r * 64 + lane;
            const bool pred = (lab[j] == li) && (j != i);
            const unsigned long long m = __ballot(pred);
            if (pred) {
                const int pos = base + __popcll(m & ((1ull << lane) - 1ull));
                poslist[pos] = j;
            }
            base += __popcll(m);
        }
        if (lane == 0) npos_s = base;
    }
    __syncthreads();   // drow complete (all waves) + poslist complete

    const int npos = npos_s;
    for (int p = tid; p < npos; p += 256) posd[p] = drow[poslist[p]];
    __syncthreads();

    // ---- Phase 3: hinge accumulation ----
    double sum = 0.0;
    int np_i = 0, nt_i = 0;
    #pragma unroll
    for (int kk = 0; kk < 2; ++kk) {
        const int k  = tid + kk * 256;
        const int lk = kk ? l1 : l0;
        if (lk != li) {                      // k is a negative
            const float dik = drow[k];
            for (int p = 0; p < npos; ++p) {
                // same op order as reference: (d_ij - d_ik) + margin
                const float t = (posd[p] - dik) + MARGIN;
                if (t > 1e-16f) { sum += (double)t; ++np_i; }
            }
            nt_i += npos;
        }
    }

    // ---- Phase 4: deterministic reduction ----
    double s = sum, p = (double)np_i, t = (double)nt_i;
    #pragma unroll
    for (int off = 32; off > 0; off >>= 1) {
        s += __shfl_down(s, off);
        p += __shfl_down(p, off);
        t += __shfl_down(t, off);
    }
    if (lane == 0) { red[wid] = s; red[4 + wid] = p; red[8 + wid] = t; }
    __syncthreads();
    if (tid == 0) {
        partial[i]         = red[0] + red[1] + red[2]  + red[3];
        partial[N + i]     = red[4] + red[5] + red[6]  + red[7];
        partial[2 * N + i] = red[8] + red[9] + red[10] + red[11];
    }
}

// Single-block deterministic final reduction + scalar outputs.
__global__ __launch_bounds__(256) void triplet_final_k(
    const double* __restrict__ partial, float* __restrict__ out)
{
    __shared__ double red[12];
    const int tid  = threadIdx.x;
    const int lane = tid & 63;
    const int wid  = tid >> 6;
    double a = 0.0, b = 0.0, c = 0.0;
    for (int k = tid; k < N; k += 256) {
        a += partial[k];
        b += partial[N + k];
        c += partial[2 * N + k];
    }
    #pragma unroll
    for (int off = 32; off > 0; off >>= 1) {
        a += __shfl_down(a, off);
        b += __shfl_down(b, off);
        c += __shfl_down(c, off);
    }
    if (lane == 0) { red[wid] = a; red[4 + wid] = b; red[8 + wid] = c; }
    __syncthreads();
    if (tid == 0) {
        const double sum   = red[0] + red[1] + red[2]  + red[3];
        const double npos  = red[4] + red[5] + red[6]  + red[7];
        const double ntrip = red[8] + red[9] + red[10] + red[11];
        out[0] = (float)(sum  / (npos  + 1e-16));  // loss
        out[1] = (float)(npos / (ntrip + 1e-16));  // fraction_positive
    }
}

extern "C" void kernel_launch(void* const* d_in, const int* in_sizes, int n_in,
                              void* d_out, int out_size, void* d_ws, size_t ws_size,
                              hipStream_t stream) {
    const float* emb   = (const float*)d_in[0];   // [512,128] f32
    const int*   lab   = (const int*)d_in[1];     // [512] i32
    float*       out   = (float*)d_out;           // [2] f32: loss, fraction_positive
    double*      parts = (double*)d_ws;           // 3*N doubles = 12 KB

    triplet_main_k<<<N, 256, 0, stream>>>(emb, lab, parts);
    triplet_final_k<<<1, 256, 0, stream>>>(parts, out);
}